// Round 13
// baseline (168.361 us; speedup 1.0000x reference)
//
#include <hip/hip_runtime.h>

typedef __fp16   fp16x2  __attribute__((ext_vector_type(2)));
typedef _Float16 half4   __attribute__((ext_vector_type(4)));
typedef float    floatx2 __attribute__((ext_vector_type(2)));
typedef float    floatx4 __attribute__((ext_vector_type(4)));

// Final act (once per c-step): t = 1 - 2/(2^a+1).
__device__ __forceinline__ float act_pre(float a) {
    float r = __builtin_amdgcn_rcpf(__builtin_amdgcn_exp2f(a) + 1.0f);
    return fmaf(-2.0f, r, 1.0f);
}

// Packed net1/net2 r-act: a = (a_net1, a_net2). Returns (1/(2^a0+1), 1/(2^a1+1))
// with ONE rcp via Montgomery-2 across the two components:
//   q = rcp(d0*d1);  r = q * swap(d)   (swap/broadcast fold into pk opsel).
// Ranges: hidden |a|<=29, layer-0 |a|<~25 -> product <= 2^58, no overflow.
__device__ __forceinline__ floatx2 ract2v(floatx2 a) {
    floatx2 d = { __builtin_amdgcn_exp2f(a[0]), __builtin_amdgcn_exp2f(a[1]) };
    d += 1.0f;
    float q = __builtin_amdgcn_rcpf(d[0] * d[1]);
    floatx2 ds = __builtin_shufflevector(d, d, 1, 0);
    return q * ds;
}
// L3 difference variant: r1 - r2 = (d1 - d0... ) = q*(d[1] - d[0]).
__device__ __forceinline__ float ract2s(floatx2 a) {
    floatx2 d = { __builtin_amdgcn_exp2f(a[0]), __builtin_amdgcn_exp2f(a[1]) };
    d += 1.0f;
    float q = __builtin_amdgcn_rcpf(d[0] * d[1]);
    return q * (d[1] - d[0]);
}

__device__ __forceinline__ half4 mk4s(float a, float b, float c, float d) {
    fp16x2 lo = __builtin_amdgcn_cvt_pkrtz(a, b);
    fp16x2 hi = __builtin_amdgcn_cvt_pkrtz(c, d);
    union { fp16x2 h2[2]; half4 h4; } u;
    u.h2[0] = lo; u.h2[1] = hi;
    return u.h4;
}

__global__ __launch_bounds__(256, 4) void automaton_kernel(
    const float* __restrict__ x, const float* __restrict__ Ws,
    const float* __restrict__ bs, const float* __restrict__ Wf,
    const float* __restrict__ bf, const float* __restrict__ extra,
    float* __restrict__ out, int n_groups)
{
    const float K = 2.885390081777927f;  // 2*log2(e)
    const int tid   = blockIdx.x * blockDim.x + threadIdx.x;
    const int wave  = tid >> 6;
    const int lane  = threadIdx.x & 63;
    const int col   = lane & 15;
    const int sub   = lane >> 4;
    const int obase = sub * 4;

    const floatx4 zeroC = {0.f, 0.f, 0.f, 0.f};
    const half4   ones  = {(_Float16)1.f, (_Float16)1.f, (_Float16)1.f, (_Float16)1.f};

    float ex[12];
#pragma unroll
    for (int j = 0; j < 12; ++j) ex[j] = extra[j];

    // ---- Layer 0: live cols (scaled by K), fold extra+bias into c1 ----
    float W0c[4][4], c1[4];
#pragma unroll
    for (int e = 0; e < 4; ++e) {
        const float* row = Ws + (obase + e) * 16;
        floatx4 r0 = *(const floatx4*)(row);
        floatx4 r1 = *(const floatx4*)(row + 4);
        floatx4 r2 = *(const floatx4*)(row + 8);
        floatx4 r3 = *(const floatx4*)(row + 12);
#pragma unroll
        for (int j = 0; j < 4; ++j) W0c[e][j] = r0[j] * K;
        float c = bs[obase + e];
#pragma unroll
        for (int j = 0; j < 4; ++j) c = fmaf(r1[j], ex[j], c);
#pragma unroll
        for (int j = 0; j < 4; ++j) c = fmaf(r2[j], ex[4 + j], c);
#pragma unroll
        for (int j = 0; j < 4; ++j) c = fmaf(r3[j], ex[8 + j], c);
        c1[e] = c * K;
    }

    // ---- Hidden layers 1..3: A'' = f16(-2K*W); c'' = K*b - 0.5*(A''.1) ----
    half4 aW0, aW1, aW2, aWf;
    floatx4 bC0, bC1, bC2;
    {
        floatx4 w1 = *(const floatx4*)(Ws + 256 + col * 16 + obase);
        floatx4 w2 = *(const floatx4*)(Ws + 512 + col * 16 + obase);
        floatx4 w3 = *(const floatx4*)(Ws + 768 + col * 16 + obase);
#pragma unroll
        for (int e = 0; e < 4; ++e) {
            aW0[e] = (_Float16)(w1[e] * (-2.0f * K));
            aW1[e] = (_Float16)(w2[e] * (-2.0f * K));
            aW2[e] = (_Float16)(w3[e] * (-2.0f * K));
        }
        floatx4 s0 = __builtin_amdgcn_mfma_f32_16x16x16f16(aW0, ones, zeroC, 0, 0, 0);
        floatx4 s1 = __builtin_amdgcn_mfma_f32_16x16x16f16(aW1, ones, zeroC, 0, 0, 0);
        floatx4 s2 = __builtin_amdgcn_mfma_f32_16x16x16f16(aW2, ones, zeroC, 0, 0, 0);
        floatx4 b1 = *(const floatx4*)(bs + 16 + obase);
        floatx4 b2 = *(const floatx4*)(bs + 32 + obase);
        floatx4 b3 = *(const floatx4*)(bs + 48 + obase);
#pragma unroll
        for (int e = 0; e < 4; ++e) {
            bC0[e] = fmaf(-0.5f, s0[e], K * b1[e]);
            bC1[e] = fmaf(-0.5f, s1[e], K * b2[e]);
            bC2[e] = fmaf(-0.5f, s2[e], K * b3[e]);
        }
        floatx4 wf = *(const floatx4*)(Wf + obase);
#pragma unroll
        for (int e = 0; e < 4; ++e) aWf[e] = (_Float16)(wf[e] * (-2.0f * K));
    }

    const int g      = wave * 16 + col;
    const bool valid = (g < n_groups);
    const int gl     = valid ? g : (n_groups - 1);
    const float* xp  = x + (size_t)gl * 104;   // 26 channels * 4 floats

    float acc = 0.0f;
#pragma unroll 1
    for (int c = 0; c < 26; ++c) {
        floatx4 xv = *(const floatx4*)(xp + c * 4);
        // net1 consumes (x0,x1,x2,x3); net2 the rotation (x2,x3,x0,x1):
        // pack as floatx2 lanes (net1, net2).
        floatx2 xq0 = {xv[0], xv[2]};
        floatx2 xq1 = {xv[1], xv[3]};
        floatx2 xq2 = __builtin_shufflevector(xq0, xq0, 1, 0);
        floatx2 xq3 = __builtin_shufflevector(xq1, xq1, 1, 0);

        // ---- Layer 0: packed FMA ladder -> packed paired r-act ----
        floatx2 rv[4];
#pragma unroll
        for (int e = 0; e < 4; ++e) {
            floatx2 a = {c1[e], c1[e]};
            a += W0c[e][0] * xq0;
            a += W0c[e][1] * xq1;
            a += W0c[e][2] * xq2;
            a += W0c[e][3] * xq3;
            rv[e] = ract2v(a);
        }
        half4 hb1 = mk4s(rv[0][0], rv[1][0], rv[2][0], rv[3][0]);
        half4 hb2 = mk4s(rv[0][1], rv[1][1], rv[2][1], rv[3][1]);

        // ---- Hidden layer 1 ----
        {
            floatx4 d1 = __builtin_amdgcn_mfma_f32_16x16x16f16(aW0, hb1, bC0, 0, 0, 0);
            floatx4 d2 = __builtin_amdgcn_mfma_f32_16x16x16f16(aW0, hb2, bC0, 0, 0, 0);
#pragma unroll
            for (int e = 0; e < 4; ++e) {
                floatx2 p = {d1[e], d2[e]};
                rv[e] = ract2v(p);
            }
            hb1 = mk4s(rv[0][0], rv[1][0], rv[2][0], rv[3][0]);
            hb2 = mk4s(rv[0][1], rv[1][1], rv[2][1], rv[3][1]);
        }
        // ---- Hidden layer 2 ----
        {
            floatx4 d1 = __builtin_amdgcn_mfma_f32_16x16x16f16(aW1, hb1, bC1, 0, 0, 0);
            floatx4 d2 = __builtin_amdgcn_mfma_f32_16x16x16f16(aW1, hb2, bC1, 0, 0, 0);
#pragma unroll
            for (int e = 0; e < 4; ++e) {
                floatx2 p = {d1[e], d2[e]};
                rv[e] = ract2v(p);
            }
            hb1 = mk4s(rv[0][0], rv[1][0], rv[2][0], rv[3][0]);
            hb2 = mk4s(rv[0][1], rv[1][1], rv[2][1], rv[3][1]);
        }
        // ---- Hidden layer 3 + fused final 16->1 (only r1-r2 needed) ----
        {
            floatx4 d1 = __builtin_amdgcn_mfma_f32_16x16x16f16(aW2, hb1, bC2, 0, 0, 0);
            floatx4 d2 = __builtin_amdgcn_mfma_f32_16x16x16f16(aW2, hb2, bC2, 0, 0, 0);
            floatx2 p0 = {d1[0], d2[0]};
            floatx2 p1 = {d1[1], d2[1]};
            floatx2 p2 = {d1[2], d2[2]};
            floatx2 p3 = {d1[3], d2[3]};
            half4 sb = mk4s(ract2s(p0), ract2s(p1), ract2s(p2), ract2s(p3));
            floatx4 dr = __builtin_amdgcn_mfma_f32_16x16x16f16(aWf, sb, zeroC, 0, 0, 0);
            acc += act_pre(dr[0]);
        }
    }
    if (lane < 16 && valid)
        out[g] = acc * 0.041875863808787856f;  // ONE_OVER_DIFF_TOT * DIFF_Q
}

extern "C" void kernel_launch(void* const* d_in, const int* in_sizes, int n_in,
                              void* d_out, int out_size, void* d_ws, size_t ws_size,
                              hipStream_t stream) {
    const float* x  = (const float*)d_in[0];
    const float* Ws = (const float*)d_in[1];
    const float* bs = (const float*)d_in[2];
    const float* Wf = (const float*)d_in[3];
    const float* bf = (const float*)d_in[4];
    const float* ex = (const float*)d_in[5];
    float* out = (float*)d_out;

    const int n_groups = out_size;              // B*N = 262144
    const int waves    = (n_groups + 15) / 16;  // 16 groups per wave
    const int blocks   = (waves + 3) / 4;       // 4 waves per block
    automaton_kernel<<<blocks, 256, 0, stream>>>(x, Ws, bs, Wf, bf, ex, out, n_groups);
}

// Round 14
// 147.814 us; speedup vs baseline: 1.1390x; 1.1390x over previous
//
#include <hip/hip_runtime.h>

typedef __fp16   fp16x2  __attribute__((ext_vector_type(2)));
typedef _Float16 half4   __attribute__((ext_vector_type(4)));
typedef float    floatx2 __attribute__((ext_vector_type(2)));
typedef float    floatx4 __attribute__((ext_vector_type(4)));

__device__ __forceinline__ floatx2 exp2p(floatx2 a) {
    floatx2 r = { __builtin_amdgcn_exp2f(a[0]), __builtin_amdgcn_exp2f(a[1]) };
    return r;
}
__device__ __forceinline__ floatx2 rcpp(floatx2 a) {
    floatx2 r = { __builtin_amdgcn_rcpf(a[0]), __builtin_amdgcn_rcpf(a[1]) };
    return r;
}

// Paired r-act (net1/net2) with ONE rcp per stream component (Montgomery-2),
// packed across channel-streams A/B: q = 1/(d1 d2); r1 = q d2; r2 = q d1.
// Ranges: hidden |a|<=29, layer-0 |a|<~25 -> product <= 2^58, no overflow.
__device__ __forceinline__ void ract2p(floatx2 a1, floatx2 a2,
                                       floatx2* r1, floatx2* r2) {
    floatx2 d1 = exp2p(a1) + 1.0f;
    floatx2 d2 = exp2p(a2) + 1.0f;
    floatx2 q  = rcpp(d1 * d2);
    *r1 = q * d2;
    *r2 = q * d1;
}
// L3 difference variant: r1 - r2 = q*(d2 - d1).
__device__ __forceinline__ floatx2 ract2d(floatx2 a1, floatx2 a2) {
    floatx2 d1 = exp2p(a1) + 1.0f;
    floatx2 d2 = exp2p(a2) + 1.0f;
    floatx2 q  = rcpp(d1 * d2);
    return q * (d2 - d1);
}

__device__ __forceinline__ half4 mk4f(floatx4 v) {
    fp16x2 lo = __builtin_amdgcn_cvt_pkrtz(v[0], v[1]);
    fp16x2 hi = __builtin_amdgcn_cvt_pkrtz(v[2], v[3]);
    union { fp16x2 h2[2]; half4 h4; } u;
    u.h2[0] = lo; u.h2[1] = hi;
    return u.h4;
}
// RNE scalar converts for x (halves the rounding err vs pkrtz RTZ).
__device__ __forceinline__ half4 mk4rne(floatx4 v) {
    half4 h;
    h[0] = (_Float16)v[0]; h[1] = (_Float16)v[1];
    h[2] = (_Float16)v[2]; h[3] = (_Float16)v[3];
    return h;
}

__global__ __launch_bounds__(256, 4) void automaton_kernel(
    const float* __restrict__ x, const float* __restrict__ Ws,
    const float* __restrict__ bs, const float* __restrict__ Wf,
    const float* __restrict__ bf, const float* __restrict__ extra,
    float* __restrict__ out, int n_groups)
{
    const float K = 2.885390081777927f;  // 2*log2(e)
    const int tid   = blockIdx.x * blockDim.x + threadIdx.x;
    const int wave  = tid >> 6;
    const int lane  = threadIdx.x & 63;
    const int col   = lane & 15;
    const int sub   = lane >> 4;
    const int obase = sub * 4;

    const floatx4 zeroC = {0.f, 0.f, 0.f, 0.f};
    const half4   ones  = {(_Float16)1.f, (_Float16)1.f, (_Float16)1.f, (_Float16)1.f};
    const half4   hzero = {(_Float16)0.f, (_Float16)0.f, (_Float16)0.f, (_Float16)0.f};

    float ex[12];
#pragma unroll
    for (int j = 0; j < 12; ++j) ex[j] = extra[j];

    // ---- Layer 0 as MFMA: A-frag = f16(K*W0[col][obase+e]); B-rows 4..15 are
    // constants folded into the C-frag c1C = K*(b0 + W0[:,4:16].extra); only
    // B-rows 0..3 (the x channels) are fed, via sub==0 lanes.
    half4 aL0;
    floatx4 c1C;
    {
        floatx4 w0r = *(const floatx4*)(Ws + col * 16 + obase);
#pragma unroll
        for (int e = 0; e < 4; ++e) aL0[e] = (_Float16)(w0r[e] * K);
#pragma unroll
        for (int e = 0; e < 4; ++e) {
            const float* row = Ws + (obase + e) * 16;
            floatx4 r1 = *(const floatx4*)(row + 4);
            floatx4 r2 = *(const floatx4*)(row + 8);
            floatx4 r3 = *(const floatx4*)(row + 12);
            float c = bs[obase + e];
#pragma unroll
            for (int j = 0; j < 4; ++j) c = fmaf(r1[j], ex[j], c);
#pragma unroll
            for (int j = 0; j < 4; ++j) c = fmaf(r2[j], ex[4 + j], c);
#pragma unroll
            for (int j = 0; j < 4; ++j) c = fmaf(r3[j], ex[8 + j], c);
            c1C[e] = c * K;
        }
    }

    // ---- Hidden layers 1..3: A'' = f16(-2K*W); c'' = K*b - 0.5*(A''.1) ----
    half4 aW0, aW1, aW2, aWf;
    floatx4 bC0, bC1, bC2;
    {
        floatx4 w1 = *(const floatx4*)(Ws + 256 + col * 16 + obase);
        floatx4 w2 = *(const floatx4*)(Ws + 512 + col * 16 + obase);
        floatx4 w3 = *(const floatx4*)(Ws + 768 + col * 16 + obase);
#pragma unroll
        for (int e = 0; e < 4; ++e) {
            aW0[e] = (_Float16)(w1[e] * (-2.0f * K));
            aW1[e] = (_Float16)(w2[e] * (-2.0f * K));
            aW2[e] = (_Float16)(w3[e] * (-2.0f * K));
        }
        floatx4 s0 = __builtin_amdgcn_mfma_f32_16x16x16f16(aW0, ones, zeroC, 0, 0, 0);
        floatx4 s1 = __builtin_amdgcn_mfma_f32_16x16x16f16(aW1, ones, zeroC, 0, 0, 0);
        floatx4 s2 = __builtin_amdgcn_mfma_f32_16x16x16f16(aW2, ones, zeroC, 0, 0, 0);
        floatx4 b1 = *(const floatx4*)(bs + 16 + obase);
        floatx4 b2 = *(const floatx4*)(bs + 32 + obase);
        floatx4 b3 = *(const floatx4*)(bs + 48 + obase);
#pragma unroll
        for (int e = 0; e < 4; ++e) {
            bC0[e] = fmaf(-0.5f, s0[e], K * b1[e]);
            bC1[e] = fmaf(-0.5f, s1[e], K * b2[e]);
            bC2[e] = fmaf(-0.5f, s2[e], K * b3[e]);
        }
        floatx4 wf = *(const floatx4*)(Wf + obase);
#pragma unroll
        for (int e = 0; e < 4; ++e) aWf[e] = (_Float16)(wf[e] * (-2.0f * K));
    }

    const int g      = wave * 16 + col;
    const bool valid = (g < n_groups);
    const int gl     = valid ? g : (n_groups - 1);
    const float* xp  = x + (size_t)gl * 104;   // 26 channels * 4 floats
    const bool sub0  = (sub == 0);

    floatx2 accp = {0.f, 0.f};
#pragma unroll 1
    for (int c = 0; c < 13; ++c) {
        // Two independent channel streams: A=c, B=c+13.
        floatx4 xvA = *(const floatx4*)(xp + c * 4);
        floatx4 xvB = *(const floatx4*)(xp + (c + 13) * 4);
        // x as the L0 B-fragment: rows 0..3 on sub==0 lanes, zero elsewhere.
        half4 hxA = sub0 ? mk4rne(xvA) : hzero;
        half4 hxB = sub0 ? mk4rne(xvB) : hzero;
        // net2 = rotated channels (x2,x3,x0,x1): register-pair swap.
        half4 hxAr = __builtin_shufflevector(hxA, hxA, 2, 3, 0, 1);
        half4 hxBr = __builtin_shufflevector(hxB, hxB, 2, 3, 0, 1);

        // ---- Layer 0 via MFMA (bias+extra ride in c1C) ----
        floatx4 dA1 = __builtin_amdgcn_mfma_f32_16x16x16f16(aL0, hxA,  c1C, 0, 0, 0);
        floatx4 dA2 = __builtin_amdgcn_mfma_f32_16x16x16f16(aL0, hxAr, c1C, 0, 0, 0);
        floatx4 dB1 = __builtin_amdgcn_mfma_f32_16x16x16f16(aL0, hxB,  c1C, 0, 0, 0);
        floatx4 dB2 = __builtin_amdgcn_mfma_f32_16x16x16f16(aL0, hxBr, c1C, 0, 0, 0);

        floatx4 rA1, rA2, rB1, rB2;
#pragma unroll
        for (int e = 0; e < 4; ++e) {
            floatx2 p1 = {dA1[e], dB1[e]};
            floatx2 p2 = {dA2[e], dB2[e]};
            floatx2 r1p, r2p;
            ract2p(p1, p2, &r1p, &r2p);
            rA1[e] = r1p[0]; rB1[e] = r1p[1];
            rA2[e] = r2p[0]; rB2[e] = r2p[1];
        }
        half4 hA1 = mk4f(rA1), hA2 = mk4f(rA2);
        half4 hB1 = mk4f(rB1), hB2 = mk4f(rB2);

        // ---- Hidden layer 1 ----
        {
            floatx4 e1 = __builtin_amdgcn_mfma_f32_16x16x16f16(aW0, hA1, bC0, 0, 0, 0);
            floatx4 e2 = __builtin_amdgcn_mfma_f32_16x16x16f16(aW0, hA2, bC0, 0, 0, 0);
            floatx4 e3 = __builtin_amdgcn_mfma_f32_16x16x16f16(aW0, hB1, bC0, 0, 0, 0);
            floatx4 e4 = __builtin_amdgcn_mfma_f32_16x16x16f16(aW0, hB2, bC0, 0, 0, 0);
#pragma unroll
            for (int e = 0; e < 4; ++e) {
                floatx2 p1 = {e1[e], e3[e]};
                floatx2 p2 = {e2[e], e4[e]};
                floatx2 r1p, r2p;
                ract2p(p1, p2, &r1p, &r2p);
                rA1[e] = r1p[0]; rB1[e] = r1p[1];
                rA2[e] = r2p[0]; rB2[e] = r2p[1];
            }
            hA1 = mk4f(rA1); hA2 = mk4f(rA2);
            hB1 = mk4f(rB1); hB2 = mk4f(rB2);
        }
        // ---- Hidden layer 2 ----
        {
            floatx4 e1 = __builtin_amdgcn_mfma_f32_16x16x16f16(aW1, hA1, bC1, 0, 0, 0);
            floatx4 e2 = __builtin_amdgcn_mfma_f32_16x16x16f16(aW1, hA2, bC1, 0, 0, 0);
            floatx4 e3 = __builtin_amdgcn_mfma_f32_16x16x16f16(aW1, hB1, bC1, 0, 0, 0);
            floatx4 e4 = __builtin_amdgcn_mfma_f32_16x16x16f16(aW1, hB2, bC1, 0, 0, 0);
#pragma unroll
            for (int e = 0; e < 4; ++e) {
                floatx2 p1 = {e1[e], e3[e]};
                floatx2 p2 = {e2[e], e4[e]};
                floatx2 r1p, r2p;
                ract2p(p1, p2, &r1p, &r2p);
                rA1[e] = r1p[0]; rB1[e] = r1p[1];
                rA2[e] = r2p[0]; rB2[e] = r2p[1];
            }
            hA1 = mk4f(rA1); hA2 = mk4f(rA2);
            hB1 = mk4f(rB1); hB2 = mk4f(rB2);
        }
        // ---- Hidden layer 3 + fused final 16->1 (only r1-r2 needed) ----
        {
            floatx4 e1 = __builtin_amdgcn_mfma_f32_16x16x16f16(aW2, hA1, bC2, 0, 0, 0);
            floatx4 e2 = __builtin_amdgcn_mfma_f32_16x16x16f16(aW2, hA2, bC2, 0, 0, 0);
            floatx4 e3 = __builtin_amdgcn_mfma_f32_16x16x16f16(aW2, hB1, bC2, 0, 0, 0);
            floatx4 e4 = __builtin_amdgcn_mfma_f32_16x16x16f16(aW2, hB2, bC2, 0, 0, 0);
            floatx4 sAv, sBv;
#pragma unroll
            for (int e = 0; e < 4; ++e) {
                floatx2 p1 = {e1[e], e3[e]};
                floatx2 p2 = {e2[e], e4[e]};
                floatx2 sp = ract2d(p1, p2);
                sAv[e] = sp[0]; sBv[e] = sp[1];
            }
            half4 sA = mk4f(sAv);
            half4 sB = mk4f(sBv);
            floatx4 drA = __builtin_amdgcn_mfma_f32_16x16x16f16(aWf, sA, zeroC, 0, 0, 0);
            floatx4 drB = __builtin_amdgcn_mfma_f32_16x16x16f16(aWf, sB, zeroC, 0, 0, 0);
            floatx2 drp = {drA[0], drB[0]};
            floatx2 dd  = exp2p(drp) + 1.0f;
            floatx2 rr  = rcpp(dd);
            accp += 1.0f + rr * -2.0f;
        }
    }
    if (lane < 16 && valid)
        out[g] = (accp[0] + accp[1]) * 0.041875863808787856f;  // ONE_OVER_DIFF_TOT * DIFF_Q
}

extern "C" void kernel_launch(void* const* d_in, const int* in_sizes, int n_in,
                              void* d_out, int out_size, void* d_ws, size_t ws_size,
                              hipStream_t stream) {
    const float* x  = (const float*)d_in[0];
    const float* Ws = (const float*)d_in[1];
    const float* bs = (const float*)d_in[2];
    const float* Wf = (const float*)d_in[3];
    const float* bf = (const float*)d_in[4];
    const float* ex = (const float*)d_in[5];
    float* out = (float*)d_out;

    const int n_groups = out_size;              // B*N = 262144
    const int waves    = (n_groups + 15) / 16;  // 16 groups per wave
    const int blocks   = (waves + 3) / 4;       // 4 waves per block
    automaton_kernel<<<blocks, 256, 0, stream>>>(x, Ws, bs, Wf, bf, ex, out, n_groups);
}

// Round 15
// 147.138 us; speedup vs baseline: 1.1442x; 1.0046x over previous
//
#include <hip/hip_runtime.h>

typedef __fp16   fp16x2  __attribute__((ext_vector_type(2)));
typedef _Float16 half4   __attribute__((ext_vector_type(4)));
typedef float    floatx2 __attribute__((ext_vector_type(2)));
typedef float    floatx4 __attribute__((ext_vector_type(4)));

__device__ __forceinline__ floatx2 exp2p(floatx2 a) {
    floatx2 r = { __builtin_amdgcn_exp2f(a[0]), __builtin_amdgcn_exp2f(a[1]) };
    return r;
}

// Paired r-act (net1/net2) packed across channel-streams A/B, with ONE rcp for
// all four denominators (Montgomery-4):
//   p = d1*d2 (per stream); s = pA*pB; q = rcp(s); qv = q*swap(p) = {1/pA,1/pB}
//   r1 = qv*d2; r2 = qv*d1.
// Ranges: hidden |a|<=29 -> product of 4 <= 2^116; L0 |a|<~25 -> <= 2^100;
// both < 2^127, no overflow. rcp rel-err 1e-7 + 3 rounded muls: invisible
// vs the f16 activation quantization (2.4e-4).
__device__ __forceinline__ void ract4p(floatx2 a1, floatx2 a2,
                                       floatx2* r1, floatx2* r2) {
    floatx2 d1 = exp2p(a1) + 1.0f;
    floatx2 d2 = exp2p(a2) + 1.0f;
    floatx2 p  = d1 * d2;
    float   q  = __builtin_amdgcn_rcpf(p[0] * p[1]);
    floatx2 qv = q * __builtin_shufflevector(p, p, 1, 0);
    *r1 = qv * d2;
    *r2 = qv * d1;
}
// L3 difference variant: r1 - r2 = qv*(d2 - d1).
__device__ __forceinline__ floatx2 ract4d(floatx2 a1, floatx2 a2) {
    floatx2 d1 = exp2p(a1) + 1.0f;
    floatx2 d2 = exp2p(a2) + 1.0f;
    floatx2 p  = d1 * d2;
    float   q  = __builtin_amdgcn_rcpf(p[0] * p[1]);
    floatx2 qv = q * __builtin_shufflevector(p, p, 1, 0);
    return qv * (d2 - d1);
}

__device__ __forceinline__ half4 mk4f(floatx4 v) {
    fp16x2 lo = __builtin_amdgcn_cvt_pkrtz(v[0], v[1]);
    fp16x2 hi = __builtin_amdgcn_cvt_pkrtz(v[2], v[3]);
    union { fp16x2 h2[2]; half4 h4; } u;
    u.h2[0] = lo; u.h2[1] = hi;
    return u.h4;
}
// RNE scalar converts for x (halves the rounding err vs pkrtz RTZ).
__device__ __forceinline__ half4 mk4rne(floatx4 v) {
    half4 h;
    h[0] = (_Float16)v[0]; h[1] = (_Float16)v[1];
    h[2] = (_Float16)v[2]; h[3] = (_Float16)v[3];
    return h;
}

__global__ __launch_bounds__(256, 4) void automaton_kernel(
    const float* __restrict__ x, const float* __restrict__ Ws,
    const float* __restrict__ bs, const float* __restrict__ Wf,
    const float* __restrict__ bf, const float* __restrict__ extra,
    float* __restrict__ out, int n_groups)
{
    const float K = 2.885390081777927f;  // 2*log2(e)
    const int tid   = blockIdx.x * blockDim.x + threadIdx.x;
    const int wave  = tid >> 6;
    const int lane  = threadIdx.x & 63;
    const int col   = lane & 15;
    const int sub   = lane >> 4;
    const int obase = sub * 4;

    const floatx4 zeroC = {0.f, 0.f, 0.f, 0.f};
    const half4   ones  = {(_Float16)1.f, (_Float16)1.f, (_Float16)1.f, (_Float16)1.f};
    const half4   hzero = {(_Float16)0.f, (_Float16)0.f, (_Float16)0.f, (_Float16)0.f};

    float ex[12];
#pragma unroll
    for (int j = 0; j < 12; ++j) ex[j] = extra[j];

    // ---- Layer 0 as MFMA: A-frag = f16(K*W0[col][obase+e]); B-rows 4..15 are
    // constants folded into the C-frag c1C = K*(b0 + W0[:,4:16].extra); only
    // B-rows 0..3 (the x channels) are fed, via sub==0 lanes.
    half4 aL0;
    floatx4 c1C;
    {
        floatx4 w0r = *(const floatx4*)(Ws + col * 16 + obase);
#pragma unroll
        for (int e = 0; e < 4; ++e) aL0[e] = (_Float16)(w0r[e] * K);
#pragma unroll
        for (int e = 0; e < 4; ++e) {
            const float* row = Ws + (obase + e) * 16;
            floatx4 r1 = *(const floatx4*)(row + 4);
            floatx4 r2 = *(const floatx4*)(row + 8);
            floatx4 r3 = *(const floatx4*)(row + 12);
            float c = bs[obase + e];
#pragma unroll
            for (int j = 0; j < 4; ++j) c = fmaf(r1[j], ex[j], c);
#pragma unroll
            for (int j = 0; j < 4; ++j) c = fmaf(r2[j], ex[4 + j], c);
#pragma unroll
            for (int j = 0; j < 4; ++j) c = fmaf(r3[j], ex[8 + j], c);
            c1C[e] = c * K;
        }
    }

    // ---- Hidden layers 1..3: A'' = f16(-2K*W); c'' = K*b - 0.5*(A''.1) ----
    half4 aW0, aW1, aW2, aWf;
    floatx4 bC0, bC1, bC2;
    {
        floatx4 w1 = *(const floatx4*)(Ws + 256 + col * 16 + obase);
        floatx4 w2 = *(const floatx4*)(Ws + 512 + col * 16 + obase);
        floatx4 w3 = *(const floatx4*)(Ws + 768 + col * 16 + obase);
#pragma unroll
        for (int e = 0; e < 4; ++e) {
            aW0[e] = (_Float16)(w1[e] * (-2.0f * K));
            aW1[e] = (_Float16)(w2[e] * (-2.0f * K));
            aW2[e] = (_Float16)(w3[e] * (-2.0f * K));
        }
        floatx4 s0 = __builtin_amdgcn_mfma_f32_16x16x16f16(aW0, ones, zeroC, 0, 0, 0);
        floatx4 s1 = __builtin_amdgcn_mfma_f32_16x16x16f16(aW1, ones, zeroC, 0, 0, 0);
        floatx4 s2 = __builtin_amdgcn_mfma_f32_16x16x16f16(aW2, ones, zeroC, 0, 0, 0);
        floatx4 b1 = *(const floatx4*)(bs + 16 + obase);
        floatx4 b2 = *(const floatx4*)(bs + 32 + obase);
        floatx4 b3 = *(const floatx4*)(bs + 48 + obase);
#pragma unroll
        for (int e = 0; e < 4; ++e) {
            bC0[e] = fmaf(-0.5f, s0[e], K * b1[e]);
            bC1[e] = fmaf(-0.5f, s1[e], K * b2[e]);
            bC2[e] = fmaf(-0.5f, s2[e], K * b3[e]);
        }
        floatx4 wf = *(const floatx4*)(Wf + obase);
#pragma unroll
        for (int e = 0; e < 4; ++e) aWf[e] = (_Float16)(wf[e] * (-2.0f * K));
    }

    const int g      = wave * 16 + col;
    const bool valid = (g < n_groups);
    const int gl     = valid ? g : (n_groups - 1);
    const float* xp  = x + (size_t)gl * 104;   // 26 channels * 4 floats
    const bool sub0  = (sub == 0);

    floatx2 accp = {0.f, 0.f};
#pragma unroll 1
    for (int c = 0; c < 13; ++c) {
        // Two independent channel streams: A=c, B=c+13.
        floatx4 xvA = *(const floatx4*)(xp + c * 4);
        floatx4 xvB = *(const floatx4*)(xp + (c + 13) * 4);
        // x as the L0 B-fragment: rows 0..3 on sub==0 lanes, zero elsewhere.
        half4 hxA = sub0 ? mk4rne(xvA) : hzero;
        half4 hxB = sub0 ? mk4rne(xvB) : hzero;
        // net2 = rotated channels (x2,x3,x0,x1): register-pair swap.
        half4 hxAr = __builtin_shufflevector(hxA, hxA, 2, 3, 0, 1);
        half4 hxBr = __builtin_shufflevector(hxB, hxB, 2, 3, 0, 1);

        // ---- Layer 0 via MFMA (bias+extra ride in c1C) ----
        floatx4 dA1 = __builtin_amdgcn_mfma_f32_16x16x16f16(aL0, hxA,  c1C, 0, 0, 0);
        floatx4 dA2 = __builtin_amdgcn_mfma_f32_16x16x16f16(aL0, hxAr, c1C, 0, 0, 0);
        floatx4 dB1 = __builtin_amdgcn_mfma_f32_16x16x16f16(aL0, hxB,  c1C, 0, 0, 0);
        floatx4 dB2 = __builtin_amdgcn_mfma_f32_16x16x16f16(aL0, hxBr, c1C, 0, 0, 0);

        floatx4 rA1, rA2, rB1, rB2;
#pragma unroll
        for (int e = 0; e < 4; ++e) {
            floatx2 p1 = {dA1[e], dB1[e]};
            floatx2 p2 = {dA2[e], dB2[e]};
            floatx2 r1p, r2p;
            ract4p(p1, p2, &r1p, &r2p);
            rA1[e] = r1p[0]; rB1[e] = r1p[1];
            rA2[e] = r2p[0]; rB2[e] = r2p[1];
        }
        half4 hA1 = mk4f(rA1), hA2 = mk4f(rA2);
        half4 hB1 = mk4f(rB1), hB2 = mk4f(rB2);

        // ---- Hidden layer 1 ----
        {
            floatx4 e1 = __builtin_amdgcn_mfma_f32_16x16x16f16(aW0, hA1, bC0, 0, 0, 0);
            floatx4 e2 = __builtin_amdgcn_mfma_f32_16x16x16f16(aW0, hA2, bC0, 0, 0, 0);
            floatx4 e3 = __builtin_amdgcn_mfma_f32_16x16x16f16(aW0, hB1, bC0, 0, 0, 0);
            floatx4 e4 = __builtin_amdgcn_mfma_f32_16x16x16f16(aW0, hB2, bC0, 0, 0, 0);
#pragma unroll
            for (int e = 0; e < 4; ++e) {
                floatx2 p1 = {e1[e], e3[e]};
                floatx2 p2 = {e2[e], e4[e]};
                floatx2 r1p, r2p;
                ract4p(p1, p2, &r1p, &r2p);
                rA1[e] = r1p[0]; rB1[e] = r1p[1];
                rA2[e] = r2p[0]; rB2[e] = r2p[1];
            }
            hA1 = mk4f(rA1); hA2 = mk4f(rA2);
            hB1 = mk4f(rB1); hB2 = mk4f(rB2);
        }
        // ---- Hidden layer 2 ----
        {
            floatx4 e1 = __builtin_amdgcn_mfma_f32_16x16x16f16(aW1, hA1, bC1, 0, 0, 0);
            floatx4 e2 = __builtin_amdgcn_mfma_f32_16x16x16f16(aW1, hA2, bC1, 0, 0, 0);
            floatx4 e3 = __builtin_amdgcn_mfma_f32_16x16x16f16(aW1, hB1, bC1, 0, 0, 0);
            floatx4 e4 = __builtin_amdgcn_mfma_f32_16x16x16f16(aW1, hB2, bC1, 0, 0, 0);
#pragma unroll
            for (int e = 0; e < 4; ++e) {
                floatx2 p1 = {e1[e], e3[e]};
                floatx2 p2 = {e2[e], e4[e]};
                floatx2 r1p, r2p;
                ract4p(p1, p2, &r1p, &r2p);
                rA1[e] = r1p[0]; rB1[e] = r1p[1];
                rA2[e] = r2p[0]; rB2[e] = r2p[1];
            }
            hA1 = mk4f(rA1); hA2 = mk4f(rA2);
            hB1 = mk4f(rB1); hB2 = mk4f(rB2);
        }
        // ---- Hidden layer 3 + fused final 16->1 (only r1-r2 needed) ----
        {
            floatx4 e1 = __builtin_amdgcn_mfma_f32_16x16x16f16(aW2, hA1, bC2, 0, 0, 0);
            floatx4 e2 = __builtin_amdgcn_mfma_f32_16x16x16f16(aW2, hA2, bC2, 0, 0, 0);
            floatx4 e3 = __builtin_amdgcn_mfma_f32_16x16x16f16(aW2, hB1, bC2, 0, 0, 0);
            floatx4 e4 = __builtin_amdgcn_mfma_f32_16x16x16f16(aW2, hB2, bC2, 0, 0, 0);
            floatx4 sAv, sBv;
#pragma unroll
            for (int e = 0; e < 4; ++e) {
                floatx2 p1 = {e1[e], e3[e]};
                floatx2 p2 = {e2[e], e4[e]};
                floatx2 sp = ract4d(p1, p2);
                sAv[e] = sp[0]; sBv[e] = sp[1];
            }
            half4 sA = mk4f(sAv);
            half4 sB = mk4f(sBv);
            floatx4 drA = __builtin_amdgcn_mfma_f32_16x16x16f16(aWf, sA, zeroC, 0, 0, 0);
            floatx4 drB = __builtin_amdgcn_mfma_f32_16x16x16f16(aWf, sB, zeroC, 0, 0, 0);
            // Final act epilogue: Montgomery-2 across {A,B}.
            floatx2 drp = {drA[0], drB[0]};
            floatx2 dd  = exp2p(drp) + 1.0f;
            float   qq  = __builtin_amdgcn_rcpf(dd[0] * dd[1]);
            floatx2 rr  = qq * __builtin_shufflevector(dd, dd, 1, 0);
            accp += 1.0f + rr * -2.0f;
        }
    }
    if (lane < 16 && valid)
        out[g] = (accp[0] + accp[1]) * 0.041875863808787856f;  // ONE_OVER_DIFF_TOT * DIFF_Q
}

extern "C" void kernel_launch(void* const* d_in, const int* in_sizes, int n_in,
                              void* d_out, int out_size, void* d_ws, size_t ws_size,
                              hipStream_t stream) {
    const float* x  = (const float*)d_in[0];
    const float* Ws = (const float*)d_in[1];
    const float* bs = (const float*)d_in[2];
    const float* Wf = (const float*)d_in[3];
    const float* bf = (const float*)d_in[4];
    const float* ex = (const float*)d_in[5];
    float* out = (float*)d_out;

    const int n_groups = out_size;              // B*N = 262144
    const int waves    = (n_groups + 15) / 16;  // 16 groups per wave
    const int blocks   = (waves + 3) / 4;       // 4 waves per block
    automaton_kernel<<<blocks, 256, 0, stream>>>(x, Ws, bs, Wf, bf, ex, out, n_groups);
}